// Round 5
// baseline (10487.924 us; speedup 1.0000x reference)
//
#include <hip/hip_runtime.h>
#include <hip/hip_bf16.h>
#include <cstdint>

// Neural-ODE RK4, v5: 64 fat blocks, 4-row-group rotation, split arrive/wait
// flags, no buffer_inv (per-load sc0sc1 coherent reads), pipelined loads.
// Roles: block b owns h-cols [64b,+64) (phase A) and x-cols [16b,+16) (phase B)
// for ALL 4 row-groups (independent solves over batch rows [16r,+16)).
// Per eval: slots A0 A1 A2 A3 B0 B1 B2 B3; arrive right after produce, wait
// right before consume -> 3 slots of slack hide all flag/L3 latency.

#define NBLK 64
#define NTHR 256
#define X_   1024
#define H_   4096
#define T_   64
#define NEV  252

typedef __bf16 bf16_t;
typedef __attribute__((ext_vector_type(8))) __bf16 bf16x8;
typedef __attribute__((ext_vector_type(4))) float  f32x4;
typedef __attribute__((ext_vector_type(2))) uint32_t u32x2;
typedef __attribute__((ext_vector_type(4))) uint32_t u32x4;

// ---- workspace layout (bytes) ----
#define WS_FLAGS 0                          // 16 lines * 64B = 1 KB (memset 4 KB)
#define WS_YIN   4096                       // bf16 [64][1024]  (128 KB)
#define WS_H     (4096 + 131072)            // bf16 [64][4096]  (512 KB)
#define WS_NEED  (4096 + 131072 + 524288)

// flag lines (u32 index, 64B apart): [0..3]=fy cnt, [4..7]=fy gen,
// [8..11]=fh cnt, [12..15]=fh gen
#define fyc(r) (flags + (0  + (r)) * 16)
#define fyg(r) (flags + (4  + (r)) * 16)
#define fhc(r) (flags + (8  + (r)) * 16)
#define fhg(r) (flags + (12 + (r)) * 16)

// -------- coherent ops (all cross-block data at the L3 coherence point) -----
__device__ inline void store_coh_b16(bf16_t* p, float v) {
  uint32_t d = (uint32_t)__builtin_bit_cast(uint16_t, (bf16_t)v);
  asm volatile("global_store_short %0, %1, off sc0 sc1" :: "v"(p), "v"(d) : "memory");
}
__device__ inline void store_coh_b64(bf16_t* p, u32x2 v) {
  asm volatile("global_store_dwordx2 %0, %1, off sc0 sc1" :: "v"(p), "v"(v) : "memory");
}
__device__ inline void store_flag(uint32_t* p, uint32_t v) {
  asm volatile("global_store_dword %0, %1, off sc0 sc1" :: "v"(p), "v"(v) : "memory");
}
__device__ inline uint32_t load_flag(const uint32_t* p) {
  uint32_t v;
  asm volatile("global_load_dword %0, %1, off sc0 sc1\n\ts_waitcnt vmcnt(0)"
               : "=v"(v) : "v"(p) : "memory");
  return v;
}
// preload: issue only; MUST be followed by explicit vmcnt(0) before use
#define PRELOAD(V, P) \
  asm volatile("global_load_dword %0, %1, off sc0 sc1" : "=v"(V) : "v"(P))

__device__ inline uint32_t pkbf(float a, float b) {
  return (uint32_t)__builtin_bit_cast(uint16_t, (bf16_t)a)
       | ((uint32_t)__builtin_bit_cast(uint16_t, (bf16_t)b) << 16);
}

// -------- pipelined 32x coherent 16B loads + 32 MFMA (2 acc chains) ---------
#define LDG(dst, P, OFF) \
  asm volatile("global_load_dwordx4 %0, %1, off offset:" OFF " sc0 sc1" \
               : "=v"(dst) : "v"(P))
#define DECL8(P) u32x4 P##0, P##1, P##2, P##3, P##4, P##5, P##6, P##7
#define LD8(P, PTR) \
  LDG(P##0, PTR, "0");   LDG(P##1, PTR, "64");  LDG(P##2, PTR, "128"); \
  LDG(P##3, PTR, "192"); LDG(P##4, PTR, "256"); LDG(P##5, PTR, "320"); \
  LDG(P##6, PTR, "384"); LDG(P##7, PTR, "448")
#define WAITV(N) do { asm volatile("s_waitcnt vmcnt(" #N ")" ::: "memory"); \
  __builtin_amdgcn_sched_barrier(0); } while (0)
#define BC(q) __builtin_bit_cast(bf16x8, q)
#define MM8(P, WF, KB) \
  acc0 = __builtin_amdgcn_mfma_f32_16x16x32_bf16(BC(P##0), (WF)[(KB)+0], acc0, 0,0,0); \
  acc1 = __builtin_amdgcn_mfma_f32_16x16x32_bf16(BC(P##1), (WF)[(KB)+1], acc1, 0,0,0); \
  acc0 = __builtin_amdgcn_mfma_f32_16x16x32_bf16(BC(P##2), (WF)[(KB)+2], acc0, 0,0,0); \
  acc1 = __builtin_amdgcn_mfma_f32_16x16x32_bf16(BC(P##3), (WF)[(KB)+3], acc1, 0,0,0); \
  acc0 = __builtin_amdgcn_mfma_f32_16x16x32_bf16(BC(P##4), (WF)[(KB)+4], acc0, 0,0,0); \
  acc1 = __builtin_amdgcn_mfma_f32_16x16x32_bf16(BC(P##5), (WF)[(KB)+5], acc1, 0,0,0); \
  acc0 = __builtin_amdgcn_mfma_f32_16x16x32_bf16(BC(P##6), (WF)[(KB)+6], acc0, 0,0,0); \
  acc1 = __builtin_amdgcn_mfma_f32_16x16x32_bf16(BC(P##7), (WF)[(KB)+7], acc1, 0,0,0)

#define GEMM32(WF, BASEPTR, ACCOUT) do { \
  const bf16_t* _p0 = (BASEPTR); \
  const bf16_t* _p1 = _p0 + 256; const bf16_t* _p2 = _p0 + 512; \
  const bf16_t* _p3 = _p0 + 768; \
  DECL8(qa); DECL8(qb); DECL8(qc); DECL8(qd); \
  f32x4 acc0 = {0.f,0.f,0.f,0.f}, acc1 = {0.f,0.f,0.f,0.f}; \
  LD8(qa, _p0); LD8(qb, _p1); \
  WAITV(8); MM8(qa, WF, 0);  LD8(qc, _p2); \
  WAITV(8); MM8(qb, WF, 8);  LD8(qd, _p3); \
  WAITV(8); MM8(qc, WF, 16); \
  WAITV(0); MM8(qd, WF, 24); \
  ACCOUT = acc0 + acc1; \
} while (0)

__global__ void __launch_bounds__(NTHR, 1) node_rk4_kernel(
    const float* __restrict__ x, const float* __restrict__ ts,
    const float* __restrict__ W1, const float* __restrict__ b1,
    const float* __restrict__ W2, const float* __restrict__ b2,
    float* __restrict__ out, uint8_t* __restrict__ ws)
{
  uint32_t* flags = (uint32_t*)(ws + WS_FLAGS);
  bf16_t* yin  = (bf16_t*)(ws + WS_YIN);
  bf16_t* hbuf = (bf16_t*)(ws + WS_H);

  const int tid = threadIdx.x;
  const int bb  = blockIdx.x;   // 0..63: column-slice owner
  const int w   = tid >> 6;     // wave 0..3
  const int l   = tid & 63;
  const int lr  = l & 15;
  const int lh  = l >> 4;

  __shared__ float red[2][4][64][4];  // A: wave-local transpose; B: K-reduce (parity)
  __shared__ float tsl[T_];
  if (tid < T_) tsl[tid] = ts[tid];

  // ---- pack W1 B-fragments: wave w owns h-cols [bb*64 + w*16, +16), full K ----
  bf16x8 w1f[32];
  #pragma unroll
  for (int ks = 0; ks < 32; ks++)
    #pragma unroll
    for (int j = 0; j < 8; j++)
      w1f[ks][j] = (bf16_t)W1[(size_t)(ks * 32 + lh * 8 + j) * H_ + bb * 64 + w * 16 + lr];

  // ---- pack W2 B-fragments: out-cols [bb*16, +16), wave w owns K-quarter w ----
  bf16x8 w2f[32];
  #pragma unroll
  for (int ks = 0; ks < 32; ks++)
    #pragma unroll
    for (int j = 0; j < 8; j++)
      w2f[ks][j] = (bf16_t)W2[(size_t)(w * 1024 + ks * 32 + lh * 8 + j) * X_ + bb * 16 + lr];

  // ---- per-thread epilogue mapping (one output element per thread, per group) ----
  const int erow  = tid >> 4;
  const int ecol  = tid & 15;
  const int elane = (erow >> 2) * 16 + ecol;   // C/D: col=lane&15, row=(lane>>4)*4+reg
  const int ereg  = erow & 3;
  const int gcol  = bb * 16 + ecol;
  const float bias1 = b1[bb * 64 + w * 16 + lr];
  const float bias2 = b2[gcol];

  // ---- RK4 state: 4 groups x 1 element per thread, registers for whole solve ----
  float y0, y1, y2, y3, yac0 = 0.f, yac1 = 0.f, yac2 = 0.f, yac3 = 0.f;
#define INITR(R) \
  y##R = x[(size_t)((R)*16 + erow) * X_ + gcol]; \
  out[(size_t)((R)*16 + erow) * (T_ * X_) + gcol] = y##R; \
  store_coh_b16(yin + (size_t)((R)*16 + erow) * X_ + gcol, y##R)
  INITR(0); INITR(1); INITR(2); INITR(3);
#undef INITR

  // init arrivals: publish yin version 1 for all 4 groups
  asm volatile("s_waitcnt vmcnt(0)" ::: "memory");
  __syncthreads();
  if (tid == 0) {
    #pragma unroll
    for (int r = 0; r < 4; r++) {
      uint32_t old = __hip_atomic_fetch_add(fyc(r), 1u, __ATOMIC_RELAXED, __HIP_MEMORY_SCOPE_AGENT);
      if (old == 63u) store_flag(fyg(r), 1u);
    }
  }
  uint32_t pf = 0;

#define A_SLOT(R, NEXTGENPTR) do { \
  if (tid == 0) { \
    asm volatile("s_waitcnt vmcnt(0)" ::: "memory"); \
    while (pf < e) pf = load_flag(fyg(R)); \
  } \
  __syncthreads(); \
  f32x4 hacc; \
  GEMM32(w1f, yin + (size_t)((R)*16 + lr) * X_ + lh * 8, hacc); \
  hacc[0] = tanhf(hacc[0] + bias1); hacc[1] = tanhf(hacc[1] + bias1); \
  hacc[2] = tanhf(hacc[2] + bias1); hacc[3] = tanhf(hacc[3] + bias1); \
  *(f32x4*)&red[0][w][l][0] = hacc; \
  { const int trow = l >> 2, tc0 = (l & 3) * 4; \
    float v0 = red[0][w][(trow >> 2) * 16 + tc0 + 0][trow & 3]; \
    float v1 = red[0][w][(trow >> 2) * 16 + tc0 + 1][trow & 3]; \
    float v2 = red[0][w][(trow >> 2) * 16 + tc0 + 2][trow & 3]; \
    float v3 = red[0][w][(trow >> 2) * 16 + tc0 + 3][trow & 3]; \
    u32x2 pk; pk[0] = pkbf(v0, v1); pk[1] = pkbf(v2, v3); \
    store_coh_b64(hbuf + (size_t)((R)*16 + trow) * H_ + bb * 64 + w * 16 + tc0, pk); } \
  asm volatile("s_waitcnt vmcnt(0)" ::: "memory"); \
  __syncthreads(); \
  if (tid == 0) { \
    uint32_t old = __hip_atomic_fetch_add(fhc(R), 1u, __ATOMIC_RELAXED, __HIP_MEMORY_SCOPE_AGENT); \
    if (old == 64u * e - 1u) store_flag(fhg(R), e); \
    PRELOAD(pf, (NEXTGENPTR)); \
  } \
} while (0)

#define B_SLOT(R, NEXTGENPTR) do { \
  if (tid == 0) { \
    asm volatile("s_waitcnt vmcnt(0)" ::: "memory"); \
    while (pf < e) pf = load_flag(fhg(R)); \
  } \
  __syncthreads(); \
  f32x4 kacc; \
  GEMM32(w2f, hbuf + (size_t)((R)*16 + lr) * H_ + w * 1024 + lh * 8, kacc); \
  *(f32x4*)&red[(R)&1][w][l][0] = kacc; \
  __syncthreads(); \
  { float kv = red[(R)&1][0][elane][ereg] + red[(R)&1][1][elane][ereg] \
             + red[(R)&1][2][elane][ereg] + red[(R)&1][3][elane][ereg] + bias2; \
    float ypub; \
    if (ev == 0)      { yac##R = y##R + dt6 * kv; ypub = y##R + dth * kv; } \
    else if (ev == 1) { yac##R += dt3 * kv;       ypub = y##R + dth * kv; } \
    else if (ev == 2) { yac##R += dt3 * kv;       ypub = y##R + dt * kv;  } \
    else              { y##R = yac##R + dt6 * kv; ypub = y##R; } \
    store_coh_b16(yin + (size_t)((R)*16 + erow) * X_ + gcol, ypub); \
    if (ev == 3) out[(size_t)((R)*16 + erow) * (T_ * X_) + (size_t)(step + 1) * X_ + gcol] = y##R; } \
  asm volatile("s_waitcnt vmcnt(0)" ::: "memory"); \
  __syncthreads(); \
  if (tid == 0) { \
    uint32_t old = __hip_atomic_fetch_add(fyc(R), 1u, __ATOMIC_RELAXED, __HIP_MEMORY_SCOPE_AGENT); \
    if (old == 64u * (e + 1u) - 1u) store_flag(fyg(R), e + 1u); \
    PRELOAD(pf, (NEXTGENPTR)); \
  } \
} while (0)

  for (int n = 0; n < NEV; n++) {
    const uint32_t e = (uint32_t)n + 1u;
    const int step = n >> 2, ev = n & 3;
    const float dt  = tsl[step + 1] - tsl[step];
    const float dth = 0.5f * dt, dt6 = dt * (1.f / 6.f), dt3 = dt * (1.f / 3.f);
    A_SLOT(0, fyg(1)); A_SLOT(1, fyg(2)); A_SLOT(2, fyg(3)); A_SLOT(3, fhg(0));
    B_SLOT(0, fhg(1)); B_SLOT(1, fhg(2)); B_SLOT(2, fhg(3)); B_SLOT(3, fyg(0));
  }
}

extern "C" void kernel_launch(void* const* d_in, const int* in_sizes, int n_in,
                              void* d_out, int out_size, void* d_ws, size_t ws_size,
                              hipStream_t stream) {
  const float* x  = (const float*)d_in[0];
  const float* ts = (const float*)d_in[1];
  const float* W1 = (const float*)d_in[2];
  const float* b1 = (const float*)d_in[3];
  const float* W2 = (const float*)d_in[4];
  const float* b2 = (const float*)d_in[5];
  float* out = (float*)d_out;
  uint8_t* ws = (uint8_t*)d_ws;
  if (ws_size < (size_t)WS_NEED) return;
  hipMemsetAsync(d_ws, 0, 4096, stream);  // reset flag lines every launch

  void* args[] = {(void*)&x, (void*)&ts, (void*)&W1, (void*)&b1,
                  (void*)&W2, (void*)&b2, (void*)&out, (void*)&ws};
  hipError_t err = hipLaunchCooperativeKernel((void*)node_rk4_kernel,
                                              dim3(NBLK), dim3(NTHR), args, 0, stream);
  if (err != hipSuccess) {
    node_rk4_kernel<<<dim3(NBLK), dim3(NTHR), 0, stream>>>(x, ts, W1, b1, W2, b2, out, ws);
  }
}

// Round 6
// 3357.693 us; speedup vs baseline: 3.1236x; 3.1236x over previous
//
#include <hip/hip_runtime.h>
#include <hip/hip_bf16.h>
#include <cstdint>

// Neural-ODE RK4, v6: barrier-free dataflow.
// 256 blocks; block (g16,mg) owns h-cols [64*g16,+64) (phase A) and x-cols
// [16*g16,+16) (phase B) of row-group mg (rows [16*mg,+16)); the 4 row-groups
// are independent ODE solves. Synchronization is per-eval epoch flags, each
// written by exactly ONE block (no atomics, no barriers, no buffer_inv):
//   A(e): wait fB[mg][*] >= e   -> read yin -> h tile -> publish fA[mg][g16]=e
//   B(e): wait fA[mg][*] >= e   -> read h   -> RK4    -> publish fB[mg][g16]=e+1
// Anti-dependency safety comes from the DAG: a producer overwrites yin only
// after all consumers published fA, which happens after their yin reads.
// All cross-block data traffic uses sc0 sc1 (coherence point); weights stay
// in VGPRs for the whole solve.

#define NBLK 256
#define NTHR 256
#define X_   1024
#define H_   4096
#define T_   64
#define NEV  252

typedef __bf16 bf16_t;
typedef __attribute__((ext_vector_type(8))) __bf16 bf16x8;
typedef __attribute__((ext_vector_type(4))) float  f32x4;
typedef __attribute__((ext_vector_type(2))) uint32_t u32x2;
typedef __attribute__((ext_vector_type(4))) uint32_t u32x4;

// ---- workspace layout (bytes) ----
#define WS_FLAGS 0                          // 512 u32 = 2 KB (memset 4 KB)
#define WS_YIN   4096                       // bf16 [64][1024]  (128 KB)
#define WS_H     (4096 + 131072)            // bf16 [64][4096]  (512 KB)
#define WS_NEED  (4096 + 131072 + 524288)

// -------- coherent ops (cross-block data at the L3 coherence point) --------
__device__ inline void store_coh_b16(bf16_t* p, float v) {
  uint32_t d = (uint32_t)__builtin_bit_cast(uint16_t, (bf16_t)v);
  asm volatile("global_store_short %0, %1, off sc0 sc1" :: "v"(p), "v"(d) : "memory");
}
__device__ inline void store_coh_b64(bf16_t* p, u32x2 v) {
  asm volatile("global_store_dwordx2 %0, %1, off sc0 sc1" :: "v"(p), "v"(v) : "memory");
}
__device__ inline void store_flag(uint32_t* p, uint32_t v) {
  asm volatile("global_store_dword %0, %1, off sc0 sc1" :: "v"(p), "v"(v) : "memory");
}
__device__ inline uint32_t load_flag(const uint32_t* p) {
  uint32_t v;
  asm volatile("global_load_dword %0, %1, off sc0 sc1\n\ts_waitcnt vmcnt(0)"
               : "=v"(v) : "v"(p) : "memory");
  return v;
}
__device__ inline uint32_t pkbf(float a, float b) {
  return (uint32_t)__builtin_bit_cast(uint16_t, (bf16_t)a)
       | ((uint32_t)__builtin_bit_cast(uint16_t, (bf16_t)b) << 16);
}

// -------- pipelined 32x coherent 16B loads + 32 MFMA (2 acc chains) ---------
#define LDG(dst, P, OFF) \
  asm volatile("global_load_dwordx4 %0, %1, off offset:" OFF " sc0 sc1" \
               : "=v"(dst) : "v"(P))
#define DECL8(P) u32x4 P##0, P##1, P##2, P##3, P##4, P##5, P##6, P##7
#define LD8(P, PTR) \
  LDG(P##0, PTR, "0");   LDG(P##1, PTR, "64");  LDG(P##2, PTR, "128"); \
  LDG(P##3, PTR, "192"); LDG(P##4, PTR, "256"); LDG(P##5, PTR, "320"); \
  LDG(P##6, PTR, "384"); LDG(P##7, PTR, "448")
#define WAITV(N) do { asm volatile("s_waitcnt vmcnt(" #N ")" ::: "memory"); \
  __builtin_amdgcn_sched_barrier(0); } while (0)
#define BC(q) __builtin_bit_cast(bf16x8, q)
#define MM8(P, WF, KB) \
  acc0 = __builtin_amdgcn_mfma_f32_16x16x32_bf16(BC(P##0), (WF)[(KB)+0], acc0, 0,0,0); \
  acc1 = __builtin_amdgcn_mfma_f32_16x16x32_bf16(BC(P##1), (WF)[(KB)+1], acc1, 0,0,0); \
  acc0 = __builtin_amdgcn_mfma_f32_16x16x32_bf16(BC(P##2), (WF)[(KB)+2], acc0, 0,0,0); \
  acc1 = __builtin_amdgcn_mfma_f32_16x16x32_bf16(BC(P##3), (WF)[(KB)+3], acc1, 0,0,0); \
  acc0 = __builtin_amdgcn_mfma_f32_16x16x32_bf16(BC(P##4), (WF)[(KB)+4], acc0, 0,0,0); \
  acc1 = __builtin_amdgcn_mfma_f32_16x16x32_bf16(BC(P##5), (WF)[(KB)+5], acc1, 0,0,0); \
  acc0 = __builtin_amdgcn_mfma_f32_16x16x32_bf16(BC(P##6), (WF)[(KB)+6], acc0, 0,0,0); \
  acc1 = __builtin_amdgcn_mfma_f32_16x16x32_bf16(BC(P##7), (WF)[(KB)+7], acc1, 0,0,0)

#define GEMM32(WF, BASEPTR, ACCOUT) do { \
  const bf16_t* _p0 = (BASEPTR); \
  const bf16_t* _p1 = _p0 + 256; const bf16_t* _p2 = _p0 + 512; \
  const bf16_t* _p3 = _p0 + 768; \
  DECL8(qa); DECL8(qb); DECL8(qc); DECL8(qd); \
  f32x4 acc0 = {0.f,0.f,0.f,0.f}, acc1 = {0.f,0.f,0.f,0.f}; \
  LD8(qa, _p0); LD8(qb, _p1); \
  WAITV(8); MM8(qa, WF, 0);  LD8(qc, _p2); \
  WAITV(8); MM8(qb, WF, 8);  LD8(qd, _p3); \
  WAITV(8); MM8(qc, WF, 16); \
  WAITV(0); MM8(qd, WF, 24); \
  ACCOUT = acc0 + acc1; \
} while (0)

__global__ void __launch_bounds__(NTHR, 1) node_rk4_kernel(
    const float* __restrict__ x, const float* __restrict__ ts,
    const float* __restrict__ W1, const float* __restrict__ b1,
    const float* __restrict__ W2, const float* __restrict__ b2,
    float* __restrict__ out, uint8_t* __restrict__ ws)
{
  uint32_t* flags = (uint32_t*)(ws + WS_FLAGS);   // [0..255]=fB, [256..511]=fA
  bf16_t* yin  = (bf16_t*)(ws + WS_YIN);
  bf16_t* hbuf = (bf16_t*)(ws + WS_H);

  const int tid = threadIdx.x;
  const int b   = blockIdx.x;
  const int w   = tid >> 6;    // wave 0..3
  const int l   = tid & 63;
  const int lr  = l & 15;
  const int lh  = l >> 4;
  const int g16 = b >> 2;      // 0..63: column-slice owner
  const int mg  = b & 3;       // 0..3 : row group / independent solve

  uint32_t* fB = flags + mg * 64;          // yin version flags (one per producer)
  uint32_t* fA = flags + 256 + mg * 64;    // h   version flags
  uint32_t* myfB = fB + g16;
  uint32_t* myfA = fA + g16;
  uint32_t* pollB = fB + l;                // wave-0 lane l watches producer l
  uint32_t* pollA = fA + l;

  __shared__ float red[4][64][4];   // A: wave-local transpose; B: cross-wave K-reduce
  __shared__ float tsl[T_];
  if (tid < T_) tsl[tid] = ts[tid];

  // ---- pack W1 B-fragments: wave w owns h-cols [g16*64 + w*16, +16), full K ----
  bf16x8 w1f[32];
  #pragma unroll
  for (int ks = 0; ks < 32; ks++)
    #pragma unroll
    for (int j = 0; j < 8; j++)
      w1f[ks][j] = (bf16_t)W1[(size_t)(ks * 32 + lh * 8 + j) * H_ + g16 * 64 + w * 16 + lr];

  // ---- pack W2 B-fragments: out-cols [g16*16, +16), wave w owns K-quarter w ----
  bf16x8 w2f[32];
  #pragma unroll
  for (int ks = 0; ks < 32; ks++)
    #pragma unroll
    for (int j = 0; j < 8; j++)
      w2f[ks][j] = (bf16_t)W2[(size_t)(w * 1024 + ks * 32 + lh * 8 + j) * X_ + g16 * 16 + lr];

  // ---- per-thread epilogue mapping (one output element per thread) ----
  const int erow  = tid >> 4;
  const int ecol  = tid & 15;
  const int elane = (erow >> 2) * 16 + ecol;   // C/D: col=lane&15, row=(lane>>4)*4+reg
  const int ereg  = erow & 3;
  const int grow  = mg * 16 + erow;            // global batch row
  const int gcol  = g16 * 16 + ecol;           // global X column
  const float bias1 = b1[g16 * 64 + w * 16 + lr];
  const float bias2 = b2[gcol];

  // ---- RK4 state: 1 element per thread, in registers for the whole solve ----
  float y = x[(size_t)grow * X_ + gcol];
  float yac = 0.f;
  out[(size_t)grow * (T_ * X_) + gcol] = y;             // pred[:,0,:] = x (plain)
  store_coh_b16(yin + (size_t)grow * X_ + gcol, y);     // publish yin v1
  asm volatile("s_waitcnt vmcnt(0)" ::: "memory");
  __syncthreads();
  if (tid == 0) store_flag(myfB, 1u);

  for (int n = 0; n < NEV; n++) {
    const uint32_t e = (uint32_t)n + 1u;
    const int step = n >> 2, ev = n & 3;
    const float dt  = tsl[step + 1] - tsl[step];
    const float dth = 0.5f * dt, dt6 = dt * (1.f / 6.f), dt3 = dt * (1.f / 3.f);

    // ===== phase A: wait yin v(e); h tile = tanh(yin @ W1 + b1) =====
    if (w == 0) {
      uint32_t v = load_flag(pollB);
      while (v < e) { __builtin_amdgcn_s_sleep(2); v = load_flag(pollB); }
    }
    __syncthreads();
    {
      f32x4 hacc;
      GEMM32(w1f, yin + (size_t)(mg * 16 + lr) * X_ + lh * 8, hacc);
      hacc[0] = tanhf(hacc[0] + bias1); hacc[1] = tanhf(hacc[1] + bias1);
      hacc[2] = tanhf(hacc[2] + bias1); hacc[3] = tanhf(hacc[3] + bias1);
      *(f32x4*)&red[w][l][0] = hacc;          // wave-local transpose via LDS
      const int trow = l >> 2, tc0 = (l & 3) * 4;
      float v0 = red[w][(trow >> 2) * 16 + tc0 + 0][trow & 3];
      float v1 = red[w][(trow >> 2) * 16 + tc0 + 1][trow & 3];
      float v2 = red[w][(trow >> 2) * 16 + tc0 + 2][trow & 3];
      float v3 = red[w][(trow >> 2) * 16 + tc0 + 3][trow & 3];
      u32x2 pk; pk[0] = pkbf(v0, v1); pk[1] = pkbf(v2, v3);
      store_coh_b64(hbuf + (size_t)(mg * 16 + trow) * H_ + g16 * 64 + w * 16 + tc0, pk);
    }
    asm volatile("s_waitcnt vmcnt(0)" ::: "memory");
    __syncthreads();
    if (tid == 0) store_flag(myfA, e);

    // ===== phase B: wait h v(e); k tile = h @ W2 + b2; RK4 update =====
    if (w == 0) {
      uint32_t v = load_flag(pollA);
      while (v < e) { __builtin_amdgcn_s_sleep(2); v = load_flag(pollA); }
    }
    __syncthreads();
    {
      f32x4 kacc;
      GEMM32(w2f, hbuf + (size_t)(mg * 16 + lr) * H_ + w * 1024 + lh * 8, kacc);
      *(f32x4*)&red[w][l][0] = kacc;
      __syncthreads();
      float kv = red[0][elane][ereg] + red[1][elane][ereg]
               + red[2][elane][ereg] + red[3][elane][ereg] + bias2;
      float ypub;
      if (ev == 0)      { yac = y + dt6 * kv; ypub = y + dth * kv; }
      else if (ev == 1) { yac += dt3 * kv;    ypub = y + dth * kv; }
      else if (ev == 2) { yac += dt3 * kv;    ypub = y + dt * kv;  }
      else              { y = yac + dt6 * kv; ypub = y; }
      store_coh_b16(yin + (size_t)grow * X_ + gcol, ypub);
      if (ev == 3)
        out[(size_t)grow * (T_ * X_) + (size_t)(step + 1) * X_ + gcol] = y;  // plain
    }
    asm volatile("s_waitcnt vmcnt(0)" ::: "memory");
    __syncthreads();
    if (tid == 0) store_flag(myfB, e + 1u);
  }
}

extern "C" void kernel_launch(void* const* d_in, const int* in_sizes, int n_in,
                              void* d_out, int out_size, void* d_ws, size_t ws_size,
                              hipStream_t stream) {
  const float* x  = (const float*)d_in[0];
  const float* ts = (const float*)d_in[1];
  const float* W1 = (const float*)d_in[2];
  const float* b1 = (const float*)d_in[3];
  const float* W2 = (const float*)d_in[4];
  const float* b2 = (const float*)d_in[5];
  float* out = (float*)d_out;
  uint8_t* ws = (uint8_t*)d_ws;
  if (ws_size < (size_t)WS_NEED) return;
  hipMemsetAsync(d_ws, 0, 4096, stream);  // reset flag lines every launch

  void* args[] = {(void*)&x, (void*)&ts, (void*)&W1, (void*)&b1,
                  (void*)&W2, (void*)&b2, (void*)&out, (void*)&ws};
  hipError_t err = hipLaunchCooperativeKernel((void*)node_rk4_kernel,
                                              dim3(NBLK), dim3(NTHR), args, 0, stream);
  if (err != hipSuccess) {
    node_rk4_kernel<<<dim3(NBLK), dim3(NTHR), 0, stream>>>(x, ts, W1, b1, W2, b2, out, ws);
  }
}